// Round 1
// baseline (1067.856 us; speedup 1.0000x reference)
//
#include <hip/hip_runtime.h>
#include <math.h>

#define BB 4
#define HH 96
#define WW 96
#define CC 256
#define FF 256
#define HW (HH*WW)          // 9216
#define PTOT (BB*HW)        // 36864
#define NTAP 9

// workspace layout (floats):
//   w_t  : [27][9][256] transposed offset weights      = 62208
//   ys   : [PTOT][9] absolute sample y coords          = 331776
//   xs   : [PTOT][9] absolute sample x coords          = 331776
//   mk   : [PTOT][9] sigmoid mask                      = 331776
// total 1057536 floats = 4.23 MB of d_ws
#define WT_OFF 0
#define WT_SZ  (27*NTAP*CC)
#define YS_OFF (WT_OFF + WT_SZ)
#define XS_OFF (YS_OFF + PTOT*NTAP)
#define MK_OFF (XS_OFF + PTOT*NTAP)

struct alignas(16) F4 { float x, y, z, w; };

__device__ __forceinline__ F4 ldf4(const float* p) { return *(const F4*)p; }
__device__ __forceinline__ void stf4(float* p, F4 v) { *(F4*)p = v; }
__device__ __forceinline__ void fma4(F4& a, const F4& b, float s) {
    a.x = fmaf(b.x, s, a.x); a.y = fmaf(b.y, s, a.y);
    a.z = fmaf(b.z, s, a.z); a.w = fmaf(b.w, s, a.w);
}

// ---------------------------------------------------------------------------
// T: w_off [3,3,C,27] -> w_t [27,9,C]  (makes kernel A weight reads contiguous)
__global__ __launch_bounds__(256) void k_transpose(const float* __restrict__ w_off,
                                                   float* __restrict__ w_t) {
    int id = blockIdx.x * 256 + threadIdx.x;   // grid sized exactly 27*9*256
    int o   = id / (NTAP * CC);
    int r   = id - o * (NTAP * CC);
    int tap = r / CC;
    int c   = r - tap * CC;
    w_t[id] = w_off[(tap * CC + c) * 27 + o];
}

// ---------------------------------------------------------------------------
// A: 3x3 offset/mask conv -> absolute coords + sigmoid mask.
// One wave handles 4 pixels; lane <-> channel-quad (64 lanes * 4 = 256 = C).
// o-chunks of 9 map naturally to {dy, dx, mask}.
__global__ __launch_bounds__(256) void k_offset(const float* __restrict__ x,
                                                const float* __restrict__ w_t,
                                                const float* __restrict__ b_off,
                                                float* __restrict__ ys_g,
                                                float* __restrict__ xs_g,
                                                float* __restrict__ mk_g) {
    const int lane = threadIdx.x & 63;
    const int wv   = threadIdx.x >> 6;
    const int pix0 = (blockIdx.x * 4 + wv) * 4;      // 4 pixels per wave
    const int b    = pix0 / HW;
    const int rem0 = pix0 - b * HW;                  // pixels stay in one image
    const float* xb = x + (size_t)b * HW * CC;

    int hh[4], wwp[4];
#pragma unroll
    for (int p = 0; p < 4; ++p) {
        int pr = rem0 + p;
        hh[p]  = pr / WW;
        wwp[p] = pr - hh[p] * WW;
    }

    for (int oc = 0; oc < 3; ++oc) {                 // 0:dy 1:dx 2:mask
        float acc[4][9];
#pragma unroll
        for (int p = 0; p < 4; ++p)
#pragma unroll
            for (int o = 0; o < 9; ++o) acc[p][o] = 0.f;

        for (int tap = 0; tap < 9; ++tap) {
            const int ky = tap / 3 - 1, kx = tap % 3 - 1;
            F4 v[4];
#pragma unroll
            for (int p = 0; p < 4; ++p) {
                const int yy = hh[p] + ky, xx = wwp[p] + kx;
                if (yy >= 0 && yy < HH && xx >= 0 && xx < WW)
                    v[p] = ldf4(xb + (size_t)(yy * WW + xx) * CC + lane * 4);
                else
                    v[p] = F4{0.f, 0.f, 0.f, 0.f};
            }
#pragma unroll
            for (int o = 0; o < 9; ++o) {
                // contiguous 1KB row per wave: conflict-free, coalesced
                F4 wvv = ldf4(w_t + (size_t)((oc * 9 + o) * NTAP + tap) * CC + lane * 4);
#pragma unroll
                for (int p = 0; p < 4; ++p) {
                    acc[p][o] = fmaf(v[p].x, wvv.x, acc[p][o]);
                    acc[p][o] = fmaf(v[p].y, wvv.y, acc[p][o]);
                    acc[p][o] = fmaf(v[p].z, wvv.z, acc[p][o]);
                    acc[p][o] = fmaf(v[p].w, wvv.w, acc[p][o]);
                }
            }
        }
        // reduce over 64 lanes (channel dim)
#pragma unroll
        for (int p = 0; p < 4; ++p)
#pragma unroll
            for (int o = 0; o < 9; ++o) {
                float r = acc[p][o];
                r += __shfl_xor(r, 1);
                r += __shfl_xor(r, 2);
                r += __shfl_xor(r, 4);
                r += __shfl_xor(r, 8);
                r += __shfl_xor(r, 16);
                r += __shfl_xor(r, 32);
                acc[p][o] = r;
            }
        if (lane == 0) {
#pragma unroll
            for (int p = 0; p < 4; ++p) {
                const int pix = pix0 + p;
#pragma unroll
                for (int o = 0; o < 9; ++o) {
                    const float v = acc[p][o] + b_off[oc * 9 + o];
                    if (oc == 0)
                        ys_g[pix * 9 + o] = (float)(hh[p] + o / 3 - 1) + v;
                    else if (oc == 1)
                        xs_g[pix * 9 + o] = (float)(wwp[p] + o % 3 - 1) + v;
                    else
                        mk_g[pix * 9 + o] = 1.f / (1.f + expf(-v));
                }
            }
        }
    }
}

// ---------------------------------------------------------------------------
// B: fused bilinear sampling + fp32 GEMM.
// Block tile: 32 pixels x 256 F, K-loop over 9 taps x 2 halves of 128 channels.
// Thread: 4 pixels x 8 f = 32 accumulators.
__global__ __launch_bounds__(256) void k_main(const float* __restrict__ x,
                                              const float* __restrict__ w_conv,
                                              const float* __restrict__ b_conv,
                                              const float* __restrict__ ys_g,
                                              const float* __restrict__ xs_g,
                                              const float* __restrict__ mk_g,
                                              float* __restrict__ out) {
    __shared__ float S[32 * 128];        // [pixel][channel], 16 KB
    __shared__ float ysL[32 * 9], xsL[32 * 9], mkL[32 * 9];

    const int t  = threadIdx.x;
    const int pb = blockIdx.x * 32;
    const int b  = pb / HW;
    const float* xb = x + (size_t)b * HW * CC;

    for (int i = t; i < 32 * 9; i += 256) {
        ysL[i] = ys_g[pb * 9 + i];
        xsL[i] = xs_g[pb * 9 + i];
        mkL[i] = mk_g[pb * 9 + i];
    }

    const int tf = t & 31;   // compute: f = tf*8 .. tf*8+7
    const int tp = t >> 5;   // compute: pixels tp*4 .. tp*4+3
    const int c4 = t & 31;   // staging: channel quad
    const int ps = t >> 5;   // staging: pixels ps + 8*i

    F4 acc0[4], acc1[4];
#pragma unroll
    for (int i = 0; i < 4; ++i) {
        acc0[i] = F4{0.f, 0.f, 0.f, 0.f};
        acc1[i] = F4{0.f, 0.f, 0.f, 0.f};
    }

    for (int k = 0; k < NTAP; ++k) {
#pragma unroll
        for (int half = 0; half < 2; ++half) {
            const int cbase = half * 128;
            __syncthreads();           // previous compute done reading S
            // ---- stage S: bilinear sample * mask, 32 px x 128 ch
#pragma unroll
            for (int i = 0; i < 4; ++i) {
                const int p = ps + 8 * i;
                const float yy = ysL[p * 9 + k];
                const float xx = xsL[p * 9 + k];
                const float m  = mkL[p * 9 + k];
                const float y0f = floorf(yy), x0f = floorf(xx);
                const int y0 = (int)y0f, x0 = (int)x0f;
                const float wy1 = yy - y0f, wx1 = xx - x0f;
                const float wy0 = 1.f - wy1, wx0 = 1.f - wx1;
                const bool vy0 = (y0 >= 0) && (y0 < HH);
                const bool vy1 = (y0 + 1 >= 0) && (y0 + 1 < HH);
                const bool vx0 = (x0 >= 0) && (x0 < WW);
                const bool vx1 = (x0 + 1 >= 0) && (x0 + 1 < WW);
                const int y0c = min(max(y0, 0), HH - 1);
                const int y1c = min(max(y0 + 1, 0), HH - 1);
                const int x0c = min(max(x0, 0), WW - 1);
                const int x1c = min(max(x0 + 1, 0), WW - 1);
                const float f00 = (vy0 && vx0) ? wy0 * wx0 * m : 0.f;
                const float f01 = (vy0 && vx1) ? wy0 * wx1 * m : 0.f;
                const float f10 = (vy1 && vx0) ? wy1 * wx0 * m : 0.f;
                const float f11 = (vy1 && vx1) ? wy1 * wx1 * m : 0.f;
                const int ci = cbase + c4 * 4;
                F4 v00 = ldf4(xb + (size_t)(y0c * WW + x0c) * CC + ci);
                F4 v01 = ldf4(xb + (size_t)(y0c * WW + x1c) * CC + ci);
                F4 v10 = ldf4(xb + (size_t)(y1c * WW + x0c) * CC + ci);
                F4 v11 = ldf4(xb + (size_t)(y1c * WW + x1c) * CC + ci);
                F4 s;
                s.x = v00.x * f00 + v01.x * f01 + v10.x * f10 + v11.x * f11;
                s.y = v00.y * f00 + v01.y * f01 + v10.y * f10 + v11.y * f11;
                s.z = v00.z * f00 + v01.z * f01 + v10.z * f10 + v11.z * f11;
                s.w = v00.w * f00 + v01.w * f01 + v10.w * f10 + v11.w * f11;
                stf4(&S[p * 128 + c4 * 4], s);
            }
            __syncthreads();
            // ---- compute: 32 channel-quads
            const float* wk = w_conv + (size_t)(k * CC + cbase) * FF + tf * 8;
            for (int cq = 0; cq < 32; ++cq) {
                F4 sv[4];
#pragma unroll
                for (int i = 0; i < 4; ++i)
                    sv[i] = ldf4(&S[(tp * 4 + i) * 128 + cq * 4]);
                F4 wA[4], wB[4];
#pragma unroll
                for (int cj = 0; cj < 4; ++cj) {
                    wA[cj] = ldf4(wk + (size_t)(cq * 4 + cj) * FF);
                    wB[cj] = ldf4(wk + (size_t)(cq * 4 + cj) * FF + 4);
                }
#pragma unroll
                for (int i = 0; i < 4; ++i) {
                    fma4(acc0[i], wA[0], sv[i].x);
                    fma4(acc0[i], wA[1], sv[i].y);
                    fma4(acc0[i], wA[2], sv[i].z);
                    fma4(acc0[i], wA[3], sv[i].w);
                    fma4(acc1[i], wB[0], sv[i].x);
                    fma4(acc1[i], wB[1], sv[i].y);
                    fma4(acc1[i], wB[2], sv[i].z);
                    fma4(acc1[i], wB[3], sv[i].w);
                }
            }
        }
    }
    F4 bc0 = ldf4(b_conv + tf * 8);
    F4 bc1 = ldf4(b_conv + tf * 8 + 4);
#pragma unroll
    for (int i = 0; i < 4; ++i) {
        const int p = pb + tp * 4 + i;
        F4 o0 = acc0[i], o1 = acc1[i];
        o0.x += bc0.x; o0.y += bc0.y; o0.z += bc0.z; o0.w += bc0.w;
        o1.x += bc1.x; o1.y += bc1.y; o1.z += bc1.z; o1.w += bc1.w;
        stf4(out + (size_t)p * FF + tf * 8, o0);
        stf4(out + (size_t)p * FF + tf * 8 + 4, o1);
    }
}

// ---------------------------------------------------------------------------
extern "C" void kernel_launch(void* const* d_in, const int* in_sizes, int n_in,
                              void* d_out, int out_size, void* d_ws, size_t ws_size,
                              hipStream_t stream) {
    const float* x      = (const float*)d_in[0];
    const float* w_off  = (const float*)d_in[1];
    const float* b_off  = (const float*)d_in[2];
    const float* w_conv = (const float*)d_in[3];
    const float* b_conv = (const float*)d_in[4];
    float* out = (float*)d_out;
    float* ws  = (float*)d_ws;

    float* w_t  = ws + WT_OFF;
    float* ys_g = ws + YS_OFF;
    float* xs_g = ws + XS_OFF;
    float* mk_g = ws + MK_OFF;

    hipLaunchKernelGGL(k_transpose, dim3((27 * NTAP * CC) / 256), dim3(256), 0, stream,
                       w_off, w_t);
    hipLaunchKernelGGL(k_offset, dim3(PTOT / 16), dim3(256), 0, stream,
                       x, w_t, b_off, ys_g, xs_g, mk_g);
    hipLaunchKernelGGL(k_main, dim3(PTOT / 32), dim3(256), 0, stream,
                       x, w_conv, b_conv, ys_g, xs_g, mk_g, out);
}

// Round 2
// 750.636 us; speedup vs baseline: 1.4226x; 1.4226x over previous
//
#include <hip/hip_runtime.h>
#include <math.h>

#define BB 4
#define HH 96
#define WW 96
#define CC 256
#define FF 256
#define HW (HH*WW)          // 9216
#define PTOT (BB*HW)        // 36864
#define NTAP 9

// workspace layout (floats):
//   w_t   : [27][9][256] transposed offset weights     = 62208
//   ys    : [PTOT][9] absolute sample y coords         = 331776
//   xs    : [PTOT][9] absolute sample x coords         = 331776
//   mk    : [PTOT][9] sigmoid mask                     = 331776
//   w_frag: [16][72][64][8] bf16 B-fragments           = 294912 floats
// total ~1.35M floats = 5.4 MB of d_ws
#define WT_OFF 0
#define WT_SZ  (27*NTAP*CC)
#define YS_OFF (WT_OFF + WT_SZ)
#define XS_OFF (YS_OFF + PTOT*NTAP)
#define MK_OFF (XS_OFF + PTOT*NTAP)
#define WF_OFF (MK_OFF + PTOT*NTAP)

typedef __attribute__((ext_vector_type(8))) short short8;   // 8 bf16 (4 VGPRs)
typedef __attribute__((ext_vector_type(4))) float floatx4;  // MFMA acc

struct alignas(16) F4 { float x, y, z, w; };
__device__ __forceinline__ F4 ldf4(const float* p) { return *(const F4*)p; }

// RNE float->bf16, packed pair
__device__ __forceinline__ unsigned int pk2_bf16(float a, float b) {
    unsigned int ua = __float_as_uint(a); ua += 0x7FFFu + ((ua >> 16) & 1u);
    unsigned int ub = __float_as_uint(b); ub += 0x7FFFu + ((ub >> 16) & 1u);
    return (ua >> 16) | (ub & 0xFFFF0000u);
}

// ---------------------------------------------------------------------------
// T: w_off [3,3,C,27] -> w_t [27,9,C]
__global__ __launch_bounds__(256) void k_transpose(const float* __restrict__ w_off,
                                                   float* __restrict__ w_t) {
    int id = blockIdx.x * 256 + threadIdx.x;
    int o   = id / (NTAP * CC);
    int r   = id - o * (NTAP * CC);
    int tap = r / CC;
    int c   = r - tap * CC;
    w_t[id] = w_off[(tap * CC + c) * 27 + o];
}

// ---------------------------------------------------------------------------
// W: w_conv [9*256 k][256 f] fp32 -> bf16 B-fragments in exact MFMA load order:
//    w_frag[ft][kc][lane][j] = w_conv[kc*32 + (lane>>4)*8 + j][ft*16 + (lane&15)]
__global__ __launch_bounds__(256) void k_wfrag(const float* __restrict__ w_conv,
                                               unsigned short* __restrict__ w_frag) {
    int id = blockIdx.x * 256 + threadIdx.x;       // 16*72*64 = 73728
    int lane = id & 63;
    int kc   = (id >> 6) % 72;
    int ft   = id / (72 * 64);
    int f  = ft * 16 + (lane & 15);
    int k0 = kc * 32 + (lane >> 4) * 8;
    unsigned int u[4];
#pragma unroll
    for (int jj = 0; jj < 4; ++jj) {
        float a = w_conv[(size_t)(k0 + 2 * jj) * FF + f];
        float b = w_conv[(size_t)(k0 + 2 * jj + 1) * FF + f];
        u[jj] = pk2_bf16(a, b);
    }
    uint4 v; v.x = u[0]; v.y = u[1]; v.z = u[2]; v.w = u[3];
    *(uint4*)(w_frag + (size_t)id * 8) = v;
}

// ---------------------------------------------------------------------------
// A: 3x3 offset/mask conv -> absolute coords + sigmoid mask
__global__ __launch_bounds__(256) void k_offset(const float* __restrict__ x,
                                                const float* __restrict__ w_t,
                                                const float* __restrict__ b_off,
                                                float* __restrict__ ys_g,
                                                float* __restrict__ xs_g,
                                                float* __restrict__ mk_g) {
    const int lane = threadIdx.x & 63;
    const int wv   = threadIdx.x >> 6;
    const int pix0 = (blockIdx.x * 4 + wv) * 4;
    const int b    = pix0 / HW;
    const int rem0 = pix0 - b * HW;
    const float* xb = x + (size_t)b * HW * CC;

    int hh[4], wwp[4];
#pragma unroll
    for (int p = 0; p < 4; ++p) {
        int pr = rem0 + p;
        hh[p]  = pr / WW;
        wwp[p] = pr - hh[p] * WW;
    }

    for (int oc = 0; oc < 3; ++oc) {
        float acc[4][9];
#pragma unroll
        for (int p = 0; p < 4; ++p)
#pragma unroll
            for (int o = 0; o < 9; ++o) acc[p][o] = 0.f;

        for (int tap = 0; tap < 9; ++tap) {
            const int ky = tap / 3 - 1, kx = tap % 3 - 1;
            F4 v[4];
#pragma unroll
            for (int p = 0; p < 4; ++p) {
                const int yy = hh[p] + ky, xx = wwp[p] + kx;
                if (yy >= 0 && yy < HH && xx >= 0 && xx < WW)
                    v[p] = ldf4(xb + (size_t)(yy * WW + xx) * CC + lane * 4);
                else
                    v[p] = F4{0.f, 0.f, 0.f, 0.f};
            }
#pragma unroll
            for (int o = 0; o < 9; ++o) {
                F4 wvv = ldf4(w_t + (size_t)((oc * 9 + o) * NTAP + tap) * CC + lane * 4);
#pragma unroll
                for (int p = 0; p < 4; ++p) {
                    acc[p][o] = fmaf(v[p].x, wvv.x, acc[p][o]);
                    acc[p][o] = fmaf(v[p].y, wvv.y, acc[p][o]);
                    acc[p][o] = fmaf(v[p].z, wvv.z, acc[p][o]);
                    acc[p][o] = fmaf(v[p].w, wvv.w, acc[p][o]);
                }
            }
        }
#pragma unroll
        for (int p = 0; p < 4; ++p)
#pragma unroll
            for (int o = 0; o < 9; ++o) {
                float r = acc[p][o];
                r += __shfl_xor(r, 1);
                r += __shfl_xor(r, 2);
                r += __shfl_xor(r, 4);
                r += __shfl_xor(r, 8);
                r += __shfl_xor(r, 16);
                r += __shfl_xor(r, 32);
                acc[p][o] = r;
            }
        if (lane == 0) {
#pragma unroll
            for (int p = 0; p < 4; ++p) {
                const int pix = pix0 + p;
#pragma unroll
                for (int o = 0; o < 9; ++o) {
                    const float v = acc[p][o] + b_off[oc * 9 + o];
                    if (oc == 0)
                        ys_g[pix * 9 + o] = (float)(hh[p] + o / 3 - 1) + v;
                    else if (oc == 1)
                        xs_g[pix * 9 + o] = (float)(wwp[p] + o % 3 - 1) + v;
                    else
                        mk_g[pix * 9 + o] = 1.f / (1.f + expf(-v));
                }
            }
        }
    }
}

// ---------------------------------------------------------------------------
// B: fused bilinear sampling (fp32 -> bf16 LDS) + MFMA GEMM.
// Tile: 64 px x 256 f per block (4 waves; wave = 64 f). K-loop: 9 taps x 8 chunks.
__global__ __launch_bounds__(256) void k_main(const float* __restrict__ x,
                                              const unsigned short* __restrict__ w_frag,
                                              const float* __restrict__ b_conv,
                                              const float* __restrict__ ys_g,
                                              const float* __restrict__ xs_g,
                                              const float* __restrict__ mk_g,
                                              float* __restrict__ out) {
    // S[px][ch] bf16, padded 256->264: px stride 528 B -> bank stride 4,
    // A-frag quad reads are 2-way conflicts (free per m136).
    __shared__ unsigned short S[64 * 264];      // 33.8 KB

    const int t    = threadIdx.x;
    const int lane = t & 63;
    const int wv   = t >> 6;
    const int pb   = blockIdx.x * 64;
    const int base = (pb / HW) * HW * CC;       // tile stays in one image

    const int spx = t & 63;                     // staging: pixel
    const int scb = wv * 64;                    // staging: channel quarter
    const int ml = lane & 15, q = lane >> 4;    // compute
    const int f0 = wv * 64;

    floatx4 acc[4][4];                          // [ntile][mtile]
#pragma unroll
    for (int i = 0; i < 4; ++i)
#pragma unroll
        for (int j = 0; j < 4; ++j) acc[i][j] = floatx4{0.f, 0.f, 0.f, 0.f};

    const short8* Wf = (const short8*)w_frag;

    for (int tap = 0; tap < NTAP; ++tap) {
        __syncthreads();                        // S consumed by previous tap
        const int gp = pb + spx;
        const float yy = ys_g[gp * 9 + tap];
        const float xx = xs_g[gp * 9 + tap];
        const float m  = mk_g[gp * 9 + tap];
        const float y0f = floorf(yy), x0f = floorf(xx);
        const int y0 = (int)y0f, x0 = (int)x0f;
        const float wy1 = yy - y0f, wx1 = xx - x0f;
        const float wy0 = 1.f - wy1, wx0 = 1.f - wx1;
        const bool vy0 = (y0 >= 0) && (y0 < HH);
        const bool vy1 = (y0 + 1 >= 0) && (y0 + 1 < HH);
        const bool vx0 = (x0 >= 0) && (x0 < WW);
        const bool vx1 = (x0 + 1 >= 0) && (x0 + 1 < WW);
        const int y0c = min(max(y0, 0), HH - 1);
        const int y1c = min(max(y0 + 1, 0), HH - 1);
        const int x0c = min(max(x0, 0), WW - 1);
        const int x1c = min(max(x0 + 1, 0), WW - 1);
        const float f00 = (vy0 && vx0) ? wy0 * wx0 * m : 0.f;
        const float f01 = (vy0 && vx1) ? wy0 * wx1 * m : 0.f;
        const float f10 = (vy1 && vx0) ? wy1 * wx0 * m : 0.f;
        const float f11 = (vy1 && vx1) ? wy1 * wx1 * m : 0.f;
        const float* p00 = x + base + (y0c * WW + x0c) * CC;
        const float* p01 = x + base + (y0c * WW + x1c) * CC;
        const float* p10 = x + base + (y1c * WW + x0c) * CC;
        const float* p11 = x + base + (y1c * WW + x1c) * CC;
#pragma unroll
        for (int g = 0; g < 8; ++g) {
            const int ch = scb + g * 8;
            F4 a0 = ldf4(p00 + ch), a1 = ldf4(p00 + ch + 4);
            F4 b0 = ldf4(p01 + ch), b1 = ldf4(p01 + ch + 4);
            F4 c0 = ldf4(p10 + ch), c1 = ldf4(p10 + ch + 4);
            F4 d0 = ldf4(p11 + ch), d1 = ldf4(p11 + ch + 4);
            float s0 = a0.x * f00 + b0.x * f01 + c0.x * f10 + d0.x * f11;
            float s1 = a0.y * f00 + b0.y * f01 + c0.y * f10 + d0.y * f11;
            float s2 = a0.z * f00 + b0.z * f01 + c0.z * f10 + d0.z * f11;
            float s3 = a0.w * f00 + b0.w * f01 + c0.w * f10 + d0.w * f11;
            float s4 = a1.x * f00 + b1.x * f01 + c1.x * f10 + d1.x * f11;
            float s5 = a1.y * f00 + b1.y * f01 + c1.y * f10 + d1.y * f11;
            float s6 = a1.z * f00 + b1.z * f01 + c1.z * f10 + d1.z * f11;
            float s7 = a1.w * f00 + b1.w * f01 + c1.w * f10 + d1.w * f11;
            uint4 v;
            v.x = pk2_bf16(s0, s1); v.y = pk2_bf16(s2, s3);
            v.z = pk2_bf16(s4, s5); v.w = pk2_bf16(s6, s7);
            *(uint4*)&S[spx * 264 + ch] = v;
        }
        __syncthreads();
#pragma unroll
        for (int kc = 0; kc < 8; ++kc) {
            short8 a[4];
#pragma unroll
            for (int mt = 0; mt < 4; ++mt)
                a[mt] = *(const short8*)&S[(mt * 16 + ml) * 264 + kc * 32 + q * 8];
#pragma unroll
            for (int nt = 0; nt < 4; ++nt) {
                short8 b = Wf[(size_t)(((wv * 4 + nt) * 72) + tap * 8 + kc) * 64 + lane];
#pragma unroll
                for (int mt = 0; mt < 4; ++mt)
                    acc[nt][mt] = __builtin_amdgcn_mfma_f32_16x16x32_bf16(a[mt], b, acc[nt][mt], 0, 0, 0);
            }
        }
    }
    // epilogue: C/D layout col=lane&15 (f), row=(lane>>4)*4+reg (px)
#pragma unroll
    for (int nt = 0; nt < 4; ++nt) {
        const int f = f0 + nt * 16 + ml;
        const float bc = b_conv[f];
#pragma unroll
        for (int mt = 0; mt < 4; ++mt) {
#pragma unroll
            for (int r = 0; r < 4; ++r) {
                const int px = pb + mt * 16 + q * 4 + r;
                out[(size_t)px * FF + f] = acc[nt][mt][r] + bc;
            }
        }
    }
}

// ---------------------------------------------------------------------------
extern "C" void kernel_launch(void* const* d_in, const int* in_sizes, int n_in,
                              void* d_out, int out_size, void* d_ws, size_t ws_size,
                              hipStream_t stream) {
    const float* x      = (const float*)d_in[0];
    const float* w_off  = (const float*)d_in[1];
    const float* b_off  = (const float*)d_in[2];
    const float* w_conv = (const float*)d_in[3];
    const float* b_conv = (const float*)d_in[4];
    float* out = (float*)d_out;
    float* ws  = (float*)d_ws;

    float* w_t  = ws + WT_OFF;
    float* ys_g = ws + YS_OFF;
    float* xs_g = ws + XS_OFF;
    float* mk_g = ws + MK_OFF;
    unsigned short* w_frag = (unsigned short*)(ws + WF_OFF);

    hipLaunchKernelGGL(k_transpose, dim3((27 * NTAP * CC) / 256), dim3(256), 0, stream,
                       w_off, w_t);
    hipLaunchKernelGGL(k_wfrag, dim3((16 * 72 * 64) / 256), dim3(256), 0, stream,
                       w_conv, w_frag);
    hipLaunchKernelGGL(k_offset, dim3(PTOT / 16), dim3(256), 0, stream,
                       x, w_t, b_off, ys_g, xs_g, mk_g);
    hipLaunchKernelGGL(k_main, dim3(PTOT / 64), dim3(256), 0, stream,
                       x, w_frag, b_conv, ys_g, xs_g, mk_g, out);
}

// Round 3
// 310.362 us; speedup vs baseline: 3.4407x; 2.4186x over previous
//
#include <hip/hip_runtime.h>
#include <math.h>

#define BB 4
#define HH 96
#define WW 96
#define CC 256
#define FF 256
#define HW (HH*WW)          // 9216
#define PTOT (BB*HW)        // 36864
#define NTAP 9

// workspace layout (float units):
//   ys    : [PTOT][9]                      331776
//   xs    : [PTOT][9]                      331776
//   mk    : [PTOT][9]                      331776
//   w_frag: [16][72][64][8] bf16 (main B)  294912
//   wof   : [2][72][64][8] bf16 (off B)     36864
//   xb16  : [PTOT][256] bf16              4718592
// total ~6.05M floats = 24.2 MB
#define YS_OFF  0
#define XS_OFF  (YS_OFF + PTOT*NTAP)
#define MK_OFF  (XS_OFF + PTOT*NTAP)
#define WF_OFF  (MK_OFF + PTOT*NTAP)
#define WOF_OFF (WF_OFF + 16*72*64*8/2)
#define XB_OFF  (WOF_OFF + 2*72*64*8/2)

typedef __attribute__((ext_vector_type(8))) short short8;   // 8 bf16
typedef __attribute__((ext_vector_type(4))) float floatx4;  // MFMA acc

struct alignas(16) F4 { float x, y, z, w; };
__device__ __forceinline__ F4 ldf4(const float* p) { return *(const F4*)p; }

__device__ __forceinline__ unsigned int pk2_bf16(float a, float b) {
    unsigned int ua = __float_as_uint(a); ua += 0x7FFFu + ((ua >> 16) & 1u);
    unsigned int ub = __float_as_uint(b); ub += 0x7FFFu + ((ub >> 16) & 1u);
    return (ua >> 16) | (ub & 0xFFFF0000u);
}
__device__ __forceinline__ float blo(unsigned int u) { return __uint_as_float(u << 16); }
__device__ __forceinline__ float bhi(unsigned int u) { return __uint_as_float(u & 0xFFFF0000u); }
__device__ __forceinline__ short8 zero8() { short8 v = {0,0,0,0,0,0,0,0}; return v; }

// ---------------------------------------------------------------------------
// x fp32 -> bf16 (8 elems/thread)
__global__ __launch_bounds__(256) void k_cast(const float* __restrict__ x,
                                              unsigned short* __restrict__ xb) {
    const int id = blockIdx.x * 256 + threadIdx.x;
    const F4 a = ldf4(x + (size_t)id * 8);
    const F4 b = ldf4(x + (size_t)id * 8 + 4);
    uint4 v;
    v.x = pk2_bf16(a.x, a.y); v.y = pk2_bf16(a.z, a.w);
    v.z = pk2_bf16(b.x, b.y); v.w = pk2_bf16(b.z, b.w);
    *(uint4*)(xb + (size_t)id * 8) = v;
}

// ---------------------------------------------------------------------------
// w_conv [2304 k][256 f] fp32 -> bf16 B-fragments:
// w_frag[ft][kc][lane][j] = w_conv[kc*32+(lane>>4)*8+j][ft*16+(lane&15)]
__global__ __launch_bounds__(256) void k_wfrag(const float* __restrict__ w_conv,
                                               unsigned short* __restrict__ w_frag) {
    const int id = blockIdx.x * 256 + threadIdx.x;   // 16*72*64
    const int lane = id & 63;
    const int kc   = (id >> 6) % 72;
    const int ft   = id / (72 * 64);
    const int f  = ft * 16 + (lane & 15);
    const int k0 = kc * 32 + (lane >> 4) * 8;
    unsigned int u[4];
#pragma unroll
    for (int jj = 0; jj < 4; ++jj) {
        float a = w_conv[(size_t)(k0 + 2 * jj) * FF + f];
        float b = w_conv[(size_t)(k0 + 2 * jj + 1) * FF + f];
        u[jj] = pk2_bf16(a, b);
    }
    uint4 v; v.x = u[0]; v.y = u[1]; v.z = u[2]; v.w = u[3];
    *(uint4*)(w_frag + (size_t)id * 8) = v;
}

// ---------------------------------------------------------------------------
// w_off [2304 k][27 o] fp32 -> bf16 B-fragments, o padded to 32 (2 n-tiles)
__global__ __launch_bounds__(256) void k_wofrag(const float* __restrict__ w_off,
                                                unsigned short* __restrict__ wof) {
    const int id = blockIdx.x * 256 + threadIdx.x;   // 2*72*64 = 9216
    const int lane = id & 63;
    const int kc   = (id >> 6) % 72;
    const int nt   = id / (72 * 64);
    const int o  = nt * 16 + (lane & 15);
    const int k0 = kc * 32 + (lane >> 4) * 8;
    unsigned int u[4];
#pragma unroll
    for (int jj = 0; jj < 4; ++jj) {
        float a = (o < 27) ? w_off[(size_t)(k0 + 2 * jj) * 27 + o] : 0.f;
        float b = (o < 27) ? w_off[(size_t)(k0 + 2 * jj + 1) * 27 + o] : 0.f;
        u[jj] = pk2_bf16(a, b);
    }
    uint4 v; v.x = u[0]; v.y = u[1]; v.z = u[2]; v.w = u[3];
    *(uint4*)(wof + (size_t)id * 8) = v;
}

// ---------------------------------------------------------------------------
// Offset/mask conv as MFMA GEMM: om[36864, 32pad] = im2col(x_bf16) . wof
// Block = 64 px (4 waves x 16-px m-tile), no LDS. XCD-swizzled.
__global__ __launch_bounds__(256) void k_offset(const unsigned short* __restrict__ xb,
                                                const unsigned short* __restrict__ wof,
                                                const float* __restrict__ b_off,
                                                float* __restrict__ ys_g,
                                                float* __restrict__ xs_g,
                                                float* __restrict__ mk_g) {
    const int lane = threadIdx.x & 63;
    const int wv   = threadIdx.x >> 6;
    const int tb   = (blockIdx.x & 7) * 72 + (blockIdx.x >> 3);   // XCD-local region
    const int pb   = tb * 64;
    const int ml = lane & 15, q = lane >> 4;

    const int px = pb + wv * 16 + ml;          // A-row this lane loads
    const int b  = px / HW;
    const int rr = px - b * HW;
    const int py = rr / WW;
    const int pxx = rr - py * WW;
    const size_t ibase = (size_t)b * HW * CC;

    floatx4 acc0 = {0.f,0.f,0.f,0.f}, acc1 = {0.f,0.f,0.f,0.f};
    const short8* W = (const short8*)wof;

    for (int tap = 0; tap < NTAP; ++tap) {
        const int sy = py + tap / 3 - 1;
        const int sx = pxx + tap % 3 - 1;
        const bool valid = (sy >= 0) && (sy < HH) && (sx >= 0) && (sx < WW);
        const unsigned short* rowp = xb + ibase + (size_t)(sy * WW + sx) * CC + q * 8;
#pragma unroll
        for (int c8 = 0; c8 < 8; ++c8) {
            short8 a = valid ? *(const short8*)(rowp + c8 * 32) : zero8();
            const int kc = tap * 8 + c8;
            acc0 = __builtin_amdgcn_mfma_f32_16x16x32_bf16(a, W[(size_t)(0 * 72 + kc) * 64 + lane], acc0, 0, 0, 0);
            acc1 = __builtin_amdgcn_mfma_f32_16x16x32_bf16(a, W[(size_t)(1 * 72 + kc) * 64 + lane], acc1, 0, 0, 0);
        }
    }
    // epilogue: lane holds (px = pb+wv*16+q*4+r, o = nt*16+ml)
#pragma unroll
    for (int nt = 0; nt < 2; ++nt) {
        const int o = nt * 16 + ml;
        if (o >= 27) continue;
        const float bo = b_off[o];
        const floatx4 acc = nt ? acc1 : acc0;
#pragma unroll
        for (int r = 0; r < 4; ++r) {
            const int pxe = pb + wv * 16 + q * 4 + r;
            const int re  = pxe % HW;
            const int pye = re / WW;
            const int pxe2 = re - pye * WW;
            const float v = acc[r] + bo;
            if (o < 9)
                ys_g[pxe * 9 + o] = (float)(pye + o / 3 - 1) + v;
            else if (o < 18) {
                const int oo = o - 9;
                xs_g[pxe * 9 + oo] = (float)(pxe2 + oo % 3 - 1) + v;
            } else {
                const int oo = o - 18;
                mk_g[pxe * 9 + oo] = 1.f / (1.f + expf(-v));
            }
        }
    }
}

// ---------------------------------------------------------------------------
// Main fused kernel: bilinear gather (bf16) -> LDS -> MFMA GEMM.
// Block = 32 px x 256 F, 4 waves (wave = 64 F: 2 m-tiles x 4 n-tiles).
__global__ __launch_bounds__(256) void k_main(const unsigned short* __restrict__ xb,
                                              const unsigned short* __restrict__ w_frag,
                                              const float* __restrict__ b_conv,
                                              const float* __restrict__ ys_g,
                                              const float* __restrict__ xs_g,
                                              const float* __restrict__ mk_g,
                                              float* __restrict__ out) {
    __shared__ unsigned short S[32 * 264];      // 16.9 KB, px stride 264 (pad 8)

    const int t    = threadIdx.x;
    const int lane = t & 63;
    const int wv   = t >> 6;
    const int tb   = (blockIdx.x & 7) * 144 + (blockIdx.x >> 3);   // XCD-local region
    const int pb   = tb * 32;
    const size_t ibase = (size_t)(pb / HW) * HW * CC;

    const int spx = t >> 3;                     // staging: pixel (0..31)
    const int c8  = t & 7;                      // staging: 8-ch sub-block
    const int gp  = pb + spx;
    const int ml = lane & 15, q = lane >> 4;
    const int f0 = wv * 64;

    floatx4 acc[4][2];
#pragma unroll
    for (int i = 0; i < 4; ++i) { acc[i][0] = floatx4{0.f,0.f,0.f,0.f}; acc[i][1] = floatx4{0.f,0.f,0.f,0.f}; }

    const short8* Wf = (const short8*)w_frag;

    for (int tap = 0; tap < NTAP; ++tap) {
        __syncthreads();
        const float yy = ys_g[gp * 9 + tap];
        const float xx = xs_g[gp * 9 + tap];
        const float m  = mk_g[gp * 9 + tap];
        const float y0f = floorf(yy), x0f = floorf(xx);
        const int y0 = (int)y0f, x0 = (int)x0f;
        const float wy1 = yy - y0f, wx1 = xx - x0f;
        const float wy0 = 1.f - wy1, wx0 = 1.f - wx1;
        const bool vy0 = (y0 >= 0) && (y0 < HH);
        const bool vy1 = (y0 + 1 >= 0) && (y0 + 1 < HH);
        const bool vx0 = (x0 >= 0) && (x0 < WW);
        const bool vx1 = (x0 + 1 >= 0) && (x0 + 1 < WW);
        const int y0c = min(max(y0, 0), HH - 1);
        const int y1c = min(max(y0 + 1, 0), HH - 1);
        const int x0c = min(max(x0, 0), WW - 1);
        const int x1c = min(max(x0 + 1, 0), WW - 1);
        const float f00 = (vy0 && vx0) ? wy0 * wx0 * m : 0.f;
        const float f01 = (vy0 && vx1) ? wy0 * wx1 * m : 0.f;
        const float f10 = (vy1 && vx0) ? wy1 * wx0 * m : 0.f;
        const float f11 = (vy1 && vx1) ? wy1 * wx1 * m : 0.f;
        const unsigned short* p00 = xb + ibase + (size_t)(y0c * WW + x0c) * CC;
        const unsigned short* p01 = xb + ibase + (size_t)(y0c * WW + x1c) * CC;
        const unsigned short* p10 = xb + ibase + (size_t)(y1c * WW + x0c) * CC;
        const unsigned short* p11 = xb + ibase + (size_t)(y1c * WW + x1c) * CC;
        // thread stages ch groups {c8*8 + j*64 : j=0..3} (16B each, conflict-free LDS)
#pragma unroll
        for (int j = 0; j < 4; ++j) {
            const int ch = c8 * 8 + j * 64;
            const uint4 A = *(const uint4*)(p00 + ch);
            const uint4 Bv = *(const uint4*)(p01 + ch);
            const uint4 Cv = *(const uint4*)(p10 + ch);
            const uint4 D = *(const uint4*)(p11 + ch);
            uint4 R;
            R.x = pk2_bf16(blo(A.x)*f00 + blo(Bv.x)*f01 + blo(Cv.x)*f10 + blo(D.x)*f11,
                           bhi(A.x)*f00 + bhi(Bv.x)*f01 + bhi(Cv.x)*f10 + bhi(D.x)*f11);
            R.y = pk2_bf16(blo(A.y)*f00 + blo(Bv.y)*f01 + blo(Cv.y)*f10 + blo(D.y)*f11,
                           bhi(A.y)*f00 + bhi(Bv.y)*f01 + bhi(Cv.y)*f10 + bhi(D.y)*f11);
            R.z = pk2_bf16(blo(A.z)*f00 + blo(Bv.z)*f01 + blo(Cv.z)*f10 + blo(D.z)*f11,
                           bhi(A.z)*f00 + bhi(Bv.z)*f01 + bhi(Cv.z)*f10 + bhi(D.z)*f11);
            R.w = pk2_bf16(blo(A.w)*f00 + blo(Bv.w)*f01 + blo(Cv.w)*f10 + blo(D.w)*f11,
                           bhi(A.w)*f00 + bhi(Bv.w)*f01 + bhi(Cv.w)*f10 + bhi(D.w)*f11);
            *(uint4*)&S[spx * 264 + ch] = R;
        }
        __syncthreads();
#pragma unroll
        for (int kc = 0; kc < 8; ++kc) {
            short8 a0 = *(const short8*)&S[(ml) * 264 + kc * 32 + q * 8];
            short8 a1 = *(const short8*)&S[(16 + ml) * 264 + kc * 32 + q * 8];
#pragma unroll
            for (int nt = 0; nt < 4; ++nt) {
                short8 bfr = Wf[(size_t)(((wv * 4 + nt) * 72) + tap * 8 + kc) * 64 + lane];
                acc[nt][0] = __builtin_amdgcn_mfma_f32_16x16x32_bf16(a0, bfr, acc[nt][0], 0, 0, 0);
                acc[nt][1] = __builtin_amdgcn_mfma_f32_16x16x32_bf16(a1, bfr, acc[nt][1], 0, 0, 0);
            }
        }
    }
    // epilogue: col = lane&15 (f), row = (lane>>4)*4+reg (px)
#pragma unroll
    for (int nt = 0; nt < 4; ++nt) {
        const int f = f0 + nt * 16 + ml;
        const float bc = b_conv[f];
#pragma unroll
        for (int mt = 0; mt < 2; ++mt) {
#pragma unroll
            for (int r = 0; r < 4; ++r) {
                const int px = pb + mt * 16 + q * 4 + r;
                out[(size_t)px * FF + f] = acc[nt][mt][r] + bc;
            }
        }
    }
}

// ---------------------------------------------------------------------------
extern "C" void kernel_launch(void* const* d_in, const int* in_sizes, int n_in,
                              void* d_out, int out_size, void* d_ws, size_t ws_size,
                              hipStream_t stream) {
    const float* x      = (const float*)d_in[0];
    const float* w_off  = (const float*)d_in[1];
    const float* b_off  = (const float*)d_in[2];
    const float* w_conv = (const float*)d_in[3];
    const float* b_conv = (const float*)d_in[4];
    float* out = (float*)d_out;
    float* ws  = (float*)d_ws;

    float* ys_g = ws + YS_OFF;
    float* xs_g = ws + XS_OFF;
    float* mk_g = ws + MK_OFF;
    unsigned short* w_frag = (unsigned short*)(ws + WF_OFF);
    unsigned short* wof    = (unsigned short*)(ws + WOF_OFF);
    unsigned short* xb     = (unsigned short*)(ws + XB_OFF);

    hipLaunchKernelGGL(k_cast, dim3(PTOT * CC / (256 * 8)), dim3(256), 0, stream, x, xb);
    hipLaunchKernelGGL(k_wfrag, dim3((16 * 72 * 64) / 256), dim3(256), 0, stream, w_conv, w_frag);
    hipLaunchKernelGGL(k_wofrag, dim3((2 * 72 * 64) / 256), dim3(256), 0, stream, w_off, wof);
    hipLaunchKernelGGL(k_offset, dim3(PTOT / 64), dim3(256), 0, stream,
                       xb, wof, b_off, ys_g, xs_g, mk_g);
    hipLaunchKernelGGL(k_main, dim3(PTOT / 32), dim3(256), 0, stream,
                       xb, w_frag, b_conv, ys_g, xs_g, mk_g, out);
}